// Round 1
// baseline (28.801 us; speedup 1.0000x reference)
//
#include <hip/hip_runtime.h>

#define PATCHD 75
#define COUTD  16
#define HOUT   220
#define WOUT   220
#define HWD    (HOUT * WOUT)   // 48400
#define BD     2
#define NPOS   (BD * HWD)      // 96800
#define POSB   128             // positions per block
#define CPT    8               // channels per thread (2 channel-groups)

__global__ __launch_bounds__(256, 2)
void smorph_kernel(const float* __restrict__ x,
                   const float* __restrict__ k1,
                   const float* __restrict__ k2,
                   const float* __restrict__ bias,
                   float* __restrict__ out)
{
    // Tables: a = exp(k), b = k*exp(k), for both kernels. 75x16 each, 19.2 KB total.
    __shared__ float sA1[PATCHD][COUTD];
    __shared__ float sB1[PATCHD][COUTD];
    __shared__ float sA2[PATCHD][COUTD];
    __shared__ float sB2[PATCHD][COUTD];

    for (int i = threadIdx.x; i < PATCHD * COUTD; i += 256) {
        float v1 = k1[i];
        float e1 = __expf(v1);
        (&sA1[0][0])[i] = e1;
        (&sB1[0][0])[i] = v1 * e1;
        float v2 = k2[i];
        float e2 = __expf(v2);
        (&sA2[0][0])[i] = e2;
        (&sB2[0][0])[i] = v2 * e2;
    }
    __syncthreads();

    const int tid = threadIdx.x;
    const int cg  = tid >> 7;             // channel group: 0 or 1
    const int c0  = cg * CPT;
    const int p   = blockIdx.x * POSB + (tid & 127);
    if (p >= NPOS) return;

    const int b  = (p >= HWD) ? 1 : 0;    // batch index without integer divide
    const int hw = p - b * HWD;
    const float* xp = x + (size_t)b * PATCHD * HWD + hw;

    float num1[CPT], den1[CPT], num2[CPT], den2[CPT];
    #pragma unroll
    for (int j = 0; j < CPT; ++j) {
        num1[j] = 0.f; den1[j] = 0.f; num2[j] = 0.f; den2[j] = 0.f;
    }

    #pragma unroll 5
    for (int k = 0; k < PATCHD; ++k) {
        const float xv = xp[(size_t)k * HWD];       // coalesced: lane i -> hw+i
        const float E  = __expf(xv);                // exp(x)
        const float R  = __builtin_amdgcn_rcpf(E);  // exp(-x) via v_rcp_f32
        const float t1 = E * xv;
        const float t2 = -(R * xv);

        // Wave-uniform broadcast reads, vectorized as ds_read_b128.
        float a1[CPT], b1v[CPT], a2[CPT], b2v[CPT];
        *(float4*)&a1[0]  = *(const float4*)&sA1[k][c0];
        *(float4*)&a1[4]  = *(const float4*)&sA1[k][c0 + 4];
        *(float4*)&b1v[0] = *(const float4*)&sB1[k][c0];
        *(float4*)&b1v[4] = *(const float4*)&sB1[k][c0 + 4];
        *(float4*)&a2[0]  = *(const float4*)&sA2[k][c0];
        *(float4*)&a2[4]  = *(const float4*)&sA2[k][c0 + 4];
        *(float4*)&b2v[0] = *(const float4*)&sB2[k][c0];
        *(float4*)&b2v[4] = *(const float4*)&sB2[k][c0 + 4];

        #pragma unroll
        for (int j = 0; j < CPT; ++j) {
            // dir1: v = x + k1;  contribution: den += E*a1, num += E*a1*(x + k1)
            den1[j] = fmaf(E,  a1[j],  den1[j]);
            num1[j] = fmaf(t1, a1[j],  num1[j]);
            num1[j] = fmaf(E,  b1v[j], num1[j]);
            // dir2: v = -x + k2; contribution: den += R*a2, num += R*a2*(k2 - x)
            den2[j] = fmaf(R,  a2[j],  den2[j]);
            num2[j] = fmaf(t2, a2[j],  num2[j]);
            num2[j] = fmaf(R,  b2v[j], num2[j]);
        }
    }

    const size_t obase = (size_t)b * COUTD * HWD + hw;
    #pragma unroll
    for (int j = 0; j < CPT; ++j) {
        const int c = c0 + j;
        const float y = num1[j] / den1[j] + num2[j] / den2[j] + bias[c];
        out[obase + (size_t)c * HWD] = y;
    }
}

extern "C" void kernel_launch(void* const* d_in, const int* in_sizes, int n_in,
                              void* d_out, int out_size, void* d_ws, size_t ws_size,
                              hipStream_t stream)
{
    const float* x    = (const float*)d_in[0];
    const float* k1   = (const float*)d_in[1];
    const float* k2   = (const float*)d_in[2];
    const float* bias = (const float*)d_in[3];
    float* out = (float*)d_out;

    const int nblocks = (NPOS + POSB - 1) / POSB;   // 757
    smorph_kernel<<<nblocks, 256, 0, stream>>>(x, k1, k2, bias, out);
}